// Round 1
// baseline (5872.795 us; speedup 1.0000x reference)
//
#include <hip/hip_runtime.h>

namespace {

constexpr int NB = 32, NL = 1024, NC = 128, NP = 96, KW = 5;
constexpr int TT = 32;                      // conv time-tile (conv2 outputs per block)
constexpr float INV_SQRT2 = 0.70710678118654752440f;

// ---------------- stats: means / stdev per (b,c) ----------------
__global__ void stats_kernel(const float* __restrict__ x, const float* __restrict__ mask,
                             float* __restrict__ means, float* __restrict__ stdev) {
  int b = blockIdx.x;
  int tid = threadIdx.x;
  int c = tid & 127, lh = tid >> 7;
  const float* xb = x + (size_t)b * NL * NC;
  const float* mb = mask + (size_t)b * NL * NC;
  float sum = 0.f, den = 0.f;
  for (int l = lh; l < NL; l += 2) {
    sum += xb[l * NC + c];
    den += (mb[l * NC + c] == 1.0f) ? 1.f : 0.f;
  }
  __shared__ float ssum[256], sden[256], smean[128], sden2[128];
  ssum[tid] = sum; sden[tid] = den;
  __syncthreads();
  if (lh == 0) {
    float stot = ssum[c] + ssum[c + 128];
    float dtot = sden[c] + sden[c + 128];
    float mn = stot / dtot;
    smean[c] = mn; sden2[c] = dtot;
    means[b * NC + c] = mn;
  }
  __syncthreads();
  float mn = smean[c];
  float sq = 0.f;
  for (int l = lh; l < NL; l += 2) {
    float m = mb[l * NC + c];
    float xv = (m == 0.f) ? 0.f : (xb[l * NC + c] - mn);
    sq += xv * xv;
  }
  __syncthreads();
  ssum[tid] = sq;
  __syncthreads();
  if (lh == 0) {
    stdev[b * NC + c] = sqrtf((ssum[c] + ssum[c + 128]) / sden2[c] + 1e-5f);
  }
}

// ---------------- normalize + transpose (B,L,C) -> (B,C,L) ----------------
__global__ void norm_transpose(const float* __restrict__ x, const float* __restrict__ mask,
                               const float* __restrict__ means, const float* __restrict__ stdev,
                               float* __restrict__ xt) {
  __shared__ float tile[32][33];
  int b = blockIdx.x;
  int l0 = blockIdx.y * 32;
  int c0 = blockIdx.z * 32;
  int tx = threadIdx.x;   // 0..31
  int ty = threadIdx.y;   // 0..7
  for (int i = ty; i < 32; i += 8) {
    int l = l0 + i, c = c0 + tx;
    float v = x[((size_t)b * NL + l) * NC + c];
    float m = mask[((size_t)b * NL + l) * NC + c];
    float val = (m == 0.f) ? 0.f : (v - means[b * NC + c]);
    tile[i][tx] = val / stdev[b * NC + c];
  }
  __syncthreads();
  for (int i = ty; i < 32; i += 8) {
    xt[((size_t)b * NC + c0 + i) * NL + l0 + tx] = tile[tx][i];
  }
}

// ---------------- Haar transform per row (length 1024) ----------------
__global__ void haar_kernel(const float* __restrict__ xt, float* __restrict__ freq) {
  int row = blockIdx.x;  // b*NC + c
  __shared__ float h[1024], t2[512];
  const float* src = xt + (size_t)row * NL;
  float* dst = freq + (size_t)row * NL;
  for (int i = threadIdx.x; i < 1024; i += 256) h[i] = src[i];
  __syncthreads();
  int n = 1024;
  while (n > 1) {
    int half = n >> 1;
    for (int i = threadIdx.x; i < half; i += 256) {
      float e = h[2 * i], o = h[2 * i + 1];
      dst[half + i] = (e - o) * INV_SQRT2;
      t2[i] = (e + o) * INV_SQRT2;
    }
    __syncthreads();
    for (int i = threadIdx.x; i < half; i += 256) h[i] = t2[i];
    __syncthreads();
    n = half;
  }
  if (threadIdx.x == 0) dst[0] = h[0];
}

// ---------------- fp32 NT GEMM: C[m,n] = epi(dot(A[m,:],B[n,:])) ----------------
// EPI 0: relu, 1: sigmoid
template <int EPI>
__global__ void gemm_nt(const float* __restrict__ A, const float* __restrict__ Bm,
                        float* __restrict__ Cm, int M, int N, int Kd) {
  __shared__ float As[16][65], Bs[16][65];
  int bm = blockIdx.y * 64, bn = blockIdx.x * 64;
  int tid = threadIdx.x;
  int tx = tid & 15, ty = tid >> 4;
  float acc[4][4] = {};
  for (int k0 = 0; k0 < Kd; k0 += 16) {
    int r = tid >> 2;
    int kq = (tid & 3) * 4;
    const float4 va = *reinterpret_cast<const float4*>(&A[(size_t)(bm + r) * Kd + k0 + kq]);
    As[kq + 0][r] = va.x; As[kq + 1][r] = va.y; As[kq + 2][r] = va.z; As[kq + 3][r] = va.w;
    const float4 vb = *reinterpret_cast<const float4*>(&Bm[(size_t)(bn + r) * Kd + k0 + kq]);
    Bs[kq + 0][r] = vb.x; Bs[kq + 1][r] = vb.y; Bs[kq + 2][r] = vb.z; Bs[kq + 3][r] = vb.w;
    __syncthreads();
#pragma unroll
    for (int k = 0; k < 16; ++k) {
      float a[4], bv[4];
#pragma unroll
      for (int u = 0; u < 4; ++u) { a[u] = As[k][ty * 4 + u]; bv[u] = Bs[k][tx * 4 + u]; }
#pragma unroll
      for (int i = 0; i < 4; ++i)
#pragma unroll
        for (int j = 0; j < 4; ++j) acc[i][j] += a[i] * bv[j];
    }
    __syncthreads();
  }
  for (int i = 0; i < 4; ++i)
    for (int j = 0; j < 4; ++j) {
      float v = acc[i][j];
      if (EPI == 0) v = v > 0.f ? v : 0.f;
      else          v = 1.f / (1.f + expf(-v));
      Cm[(size_t)(bm + ty * 4 + i) * N + bn + tx * 4 + j] = v;
    }
}

// ---------------- LayerNorm over last dim (1024) per row, in place ----------------
__global__ void ln_kernel(float* __restrict__ lr, const float* __restrict__ g,
                          const float* __restrict__ bta) {
  int row = blockIdx.x;
  float* p = lr + (size_t)row * 1024;
  int tid = threadIdx.x;
  float v[4];
#pragma unroll
  for (int i = 0; i < 4; ++i) v[i] = p[tid + 256 * i];
  __shared__ float red[256];
  red[tid] = v[0] + v[1] + v[2] + v[3];
  __syncthreads();
  for (int off = 128; off > 0; off >>= 1) {
    if (tid < off) red[tid] += red[tid + off];
    __syncthreads();
  }
  float mu = red[0] * (1.f / 1024.f);
  __syncthreads();
  float sq = 0.f;
#pragma unroll
  for (int i = 0; i < 4; ++i) { float d = v[i] - mu; sq += d * d; }
  red[tid] = sq;
  __syncthreads();
  for (int off = 128; off > 0; off >>= 1) {
    if (tid < off) red[tid] += red[tid + off];
    __syncthreads();
  }
  float rs = rsqrtf(red[0] * (1.f / 1024.f) + 1e-6f);
#pragma unroll
  for (int i = 0; i < 4; ++i) {
    int idx = tid + 256 * i;
    p[idx] = (v[i] - mu) * rs * g[idx] + bta[idx];
  }
}

// ---------------- positional encoding table pe[l][c] ----------------
__global__ void pe_kernel(float* __restrict__ pe) {
  int idx = blockIdx.x * 256 + threadIdx.x;  // over NL*NC
  int l = idx >> 7, c = idx & 127;
  float inc = logf(10000.f) / 63.f;
  int t = c & 63;
  float inv = expf(-inc * (float)t);
  float st = (float)l * inv;
  pe[idx] = (c < 64) ? sinf(st) : cosf(st);
}

// ---------------- x_t = x_t * lr + pe ----------------
__global__ void combine_kernel(float* __restrict__ xt, const float* __restrict__ lr,
                               const float* __restrict__ pe) {
  size_t idx = (size_t)blockIdx.x * 256 + threadIdx.x;  // over NB*NC*NL
  int l = (int)(idx & 1023);
  int c = (int)((idx >> 10) & 127);
  xt[idx] = xt[idx] * lr[idx] + pe[(l << 7) | c];
}

// ---------------- fused causal conv block + combine ----------------
// ccb = tanh(conv2(leaky(conv1(edgepad(in)))))
// mode 0: out = oth * exp(ccb);  mode 1: out = oth + ccb;  mode 2: out = oth - ccb
// in/oth/out element (b,ch,t) at base + (b*NC+ch)*row + t*ts  (base pre-offset by caller)
__global__ void ccb_kernel(const float* inp, int in_row, int in_ts,
                           const float* oth, int oth_row, int oth_ts,
                           float* __restrict__ outp, int out_row, int out_ts,
                           const float* __restrict__ w1p, const float* __restrict__ b1p,
                           const float* __restrict__ w2p, const float* __restrict__ b2p,
                           int T, int mode) {
  __shared__ float sin_[128][TT + 8];   // padded input tile
  __shared__ float smid[128][TT + 5];   // conv1 output (TT+4 valid, +1 pad)
  int b = blockIdx.x;
  int t0 = blockIdx.y * TT;
  int tid = threadIdx.x;
  const float* inb = inp + (size_t)b * NC * in_row;
  for (int idx = tid; idx < 128 * (TT + 8); idx += 256) {
    int ci = idx / (TT + 8);
    int j = idx - ci * (TT + 8);
    int t = t0 + j - 4;
    t = t < 0 ? 0 : (t >= T ? T - 1 : t);
    sin_[ci][j] = inb[(size_t)ci * in_row + (size_t)t * in_ts];
  }
  __syncthreads();
  int co = tid & 127;
  int half = tid >> 7;
  // conv1: outputs local tt in [0, TT+4)
  {
    const float* wrow = w1p + (size_t)co * NC * KW;
    float accv[18];
    float bias = b1p[co];
#pragma unroll
    for (int u = 0; u < 18; ++u) accv[u] = bias;
    int tb = half * 18;
    for (int ci = 0; ci < 128; ++ci) {
      float win[22];
#pragma unroll
      for (int u = 0; u < 22; ++u) win[u] = sin_[ci][tb + u];
#pragma unroll
      for (int k = 0; k < KW; ++k) {
        float w = wrow[ci * KW + k];
#pragma unroll
        for (int u = 0; u < 18; ++u) accv[u] += w * win[u + k];
      }
    }
#pragma unroll
    for (int u = 0; u < 18; ++u) {
      float v = accv[u];
      smid[co][tb + u] = v > 0.f ? v : 0.01f * v;
    }
  }
  __syncthreads();
  // conv2 + tanh + combine
  {
    const float* wrow = w2p + (size_t)co * NC * KW;
    float accv[16];
    float bias = b2p[co];
#pragma unroll
    for (int u = 0; u < 16; ++u) accv[u] = bias;
    int tb = half * 16;
    for (int ci = 0; ci < 128; ++ci) {
      float win[20];
#pragma unroll
      for (int u = 0; u < 20; ++u) win[u] = smid[ci][tb + u];
#pragma unroll
      for (int k = 0; k < KW; ++k) {
        float w = wrow[ci * KW + k];
#pragma unroll
        for (int u = 0; u < 16; ++u) accv[u] += w * win[u + k];
      }
    }
    const float* othb = oth + (size_t)b * NC * oth_row + (size_t)co * oth_row;
    float* outb = outp + (size_t)b * NC * out_row + (size_t)co * out_row;
#pragma unroll
    for (int u = 0; u < 16; ++u) {
      int t = t0 + tb + u;
      float cv = tanhf(accv[u]);
      float ov = othb[(size_t)t * oth_ts];
      float r;
      if (mode == 0)      r = ov * expf(cv);
      else if (mode == 1) r = ov + cv;
      else                r = ov - cv;
      outb[(size_t)t * out_ts] = r;
    }
  }
}

// ---------------- final projection + denorm, only p in [0,96), c in [0,3) ----------------
__global__ void final_kernel(const float* __restrict__ dect, const float* __restrict__ xt,
                             const float* __restrict__ projw, const float* __restrict__ means,
                             const float* __restrict__ stdev, float* __restrict__ out) {
  int b = blockIdx.x, p = blockIdx.y;
  int tid = threadIdx.x;
  const float* w = projw + (size_t)(1024 + p) * 1024;
  const float* d0 = dect + (size_t)b * NC * NL;
  const float* x0 = xt + (size_t)b * NC * NL;
  float a[3] = {0.f, 0.f, 0.f};
  for (int l = tid; l < 1024; l += 256) {
    float wv = w[l];
#pragma unroll
    for (int cc = 0; cc < 3; ++cc)
      a[cc] += wv * (d0[(size_t)cc * NL + l] + x0[(size_t)cc * NL + l]);
  }
  __shared__ float red[3][256];
  for (int cc = 0; cc < 3; ++cc) red[cc][tid] = a[cc];
  __syncthreads();
  for (int off = 128; off > 0; off >>= 1) {
    if (tid < off) {
      red[0][tid] += red[0][tid + off];
      red[1][tid] += red[1][tid + off];
      red[2][tid] += red[2][tid + off];
    }
    __syncthreads();
  }
  if (tid < 3) {
    out[((size_t)b * NP + p) * 3 + tid] = red[tid][0] * stdev[b * NC + tid] + means[b * NC + tid];
  }
}

}  // namespace

extern "C" void kernel_launch(void* const* d_in, const int* in_sizes, int n_in,
                              void* d_out, int out_size, void* d_ws, size_t ws_size,
                              hipStream_t stream) {
  (void)in_sizes; (void)n_in; (void)out_size; (void)ws_size;
  const float* x_enc = (const float*)d_in[0];
  const float* mask  = (const float*)d_in[1];
  const float* fc1_w = (const float*)d_in[2];
  const float* fc2_w = (const float*)d_in[3];
  const float* ln_g  = (const float*)d_in[4];
  const float* ln_b  = (const float*)d_in[5];
  const float* w1    = (const float*)d_in[6];
  const float* b1    = (const float*)d_in[7];
  const float* w2    = (const float*)d_in[8];
  const float* b2    = (const float*)d_in[9];
  const float* projw = (const float*)d_in[10];
  float* out = (float*)d_out;
  float* ws = (float*)d_ws;

  // workspace layout (floats); total 25,305,088 floats ~= 101 MB
  float* means = ws + 0;          // 4096
  float* stdev = ws + 4096;       // 4096
  float* pe    = ws + 8192;       // 131072
  float* x_t   = ws + 139264;     // 4,194,304  (B,C,L), kept to the end
  float* freq  = ws + 4333568;    // 4,194,304  freq -> lr -> IN3
  float* hid   = ws + 8527872;    // 8,388,608  hidden -> IN1+IN2
  float* dect  = ws + 16916480;   // 4,194,304  tree output (B,C,L)
  float* xet   = ws + 21110784;   // 2,097,152
  float* xot   = ws + 23207936;   // 2,097,152
  float* IN1 = hid;
  float* IN2 = hid + 4194304;
  float* IN3 = freq;

  stats_kernel<<<NB, 256, 0, stream>>>(x_enc, mask, means, stdev);
  norm_transpose<<<dim3(NB, NL / 32, NC / 32), dim3(32, 8), 0, stream>>>(x_enc, mask, means, stdev, x_t);
  haar_kernel<<<NB * NC, 256, 0, stream>>>(x_t, freq);
  gemm_nt<0><<<dim3(2048 / 64, 4096 / 64), 256, 0, stream>>>(freq, fc1_w, hid, 4096, 2048, 1024);
  gemm_nt<1><<<dim3(1024 / 64, 4096 / 64), 256, 0, stream>>>(hid, fc2_w, freq, 4096, 1024, 2048);
  ln_kernel<<<4096, 256, 0, stream>>>(freq, ln_g, ln_b);
  pe_kernel<<<(NL * NC) / 256, 256, 0, stream>>>(pe);
  combine_kernel<<<(NB * NC * NL) / 256, 256, 0, stream>>>(x_t, freq, pe);

  // tree: preorder node index per (depth, BFS pos)
  static const int preidx[4][8] = {
      {0, 0, 0, 0, 0, 0, 0, 0},
      {1, 8, 0, 0, 0, 0, 0, 0},
      {2, 5, 9, 12, 0, 0, 0, 0},
      {3, 4, 6, 7, 10, 11, 13, 14}};
  const size_t SEG = (size_t)NB * NC;
  float* depthbuf[4] = {x_t, IN1, IN2, IN3};
  for (int d = 0; d < 4; ++d) {
    int prow = NL >> d;
    int Tn = prow >> 1;
    int nsub = 1 << d;
    dim3 grid(NB, Tn / TT);
    for (int p = 0; p < nsub; ++p) {
      int node = preidx[d][p];
      float* par = depthbuf[d] + (size_t)p * SEG * prow;
      const float *pw1[4], *pb1[4], *pw2[4], *pb2[4];
      for (int br = 0; br < 4; ++br) {
        size_t o = (size_t)(node * 4 + br);
        pw1[br] = w1 + o * NC * NC * KW;
        pb1[br] = b1 + o * NC;
        pw2[br] = w2 + o * NC * NC * KW;
        pb2[br] = b2 + o * NC;
      }
      float *eout, *oout;
      int orow, ots;
      if (d < 3) {
        eout = depthbuf[d + 1] + (size_t)(2 * p) * SEG * Tn;
        oout = depthbuf[d + 1] + (size_t)(2 * p + 1) * SEG * Tn;
        orow = Tn; ots = 1;
      } else {
        int rev = ((p >> 2) & 1) | (((p >> 1) & 1) << 1) | ((p & 1) << 2);
        eout = dect + rev;
        oout = dect + rev + 8;
        orow = NL; ots = 16;
      }
      // xet = xe * exp(ccb0(xo))
      ccb_kernel<<<grid, 256, 0, stream>>>(par + 1, prow, 2, par, prow, 2, xet, Tn, 1,
                                           pw1[0], pb1[0], pw2[0], pb2[0], Tn, 0);
      // xot = xo * exp(ccb1(xe))
      ccb_kernel<<<grid, 256, 0, stream>>>(par, prow, 2, par + 1, prow, 2, xot, Tn, 1,
                                           pw1[1], pb1[1], pw2[1], pb2[1], Tn, 0);
      // e = xet + ccb2(xot)
      ccb_kernel<<<grid, 256, 0, stream>>>(xot, Tn, 1, xet, Tn, 1, eout, orow, ots,
                                           pw1[2], pb1[2], pw2[2], pb2[2], Tn, 1);
      // o = xot - ccb3(xet)
      ccb_kernel<<<grid, 256, 0, stream>>>(xet, Tn, 1, xot, Tn, 1, oout, orow, ots,
                                           pw1[3], pb1[3], pw2[3], pb2[3], Tn, 2);
    }
  }

  final_kernel<<<dim3(NB, NP), 256, 0, stream>>>(dect, x_t, projw, means, stdev, out);
}

// Round 2
// 659.008 us; speedup vs baseline: 8.9116x; 8.9116x over previous
//
#include <hip/hip_runtime.h>

namespace {

constexpr int NB = 32, NL = 1024, NC = 128, NP = 96, KW = 5;
constexpr float INV_SQRT2 = 0.70710678118654752440f;

typedef unsigned short u16;
typedef __attribute__((ext_vector_type(4))) u16 u16x4;
typedef __attribute__((ext_vector_type(8))) u16 u16x8;
typedef __attribute__((ext_vector_type(8))) short short8;
typedef __attribute__((ext_vector_type(4))) float f32x4;

__device__ inline u16 f2bf(float f) {
  unsigned u = __float_as_uint(f);
  u += 0x7fff + ((u >> 16) & 1);
  return (u16)(u >> 16);
}

__device__ inline float ftanh(float x) {
  float e = __expf(2.f * x);
  return 1.f - 2.f / (e + 1.f);
}

// ---------------- stats: means / stdev per (b,c) ----------------
__global__ void stats_kernel(const float* __restrict__ x, const float* __restrict__ mask,
                             float* __restrict__ means, float* __restrict__ stdev) {
  int b = blockIdx.x;
  int tid = threadIdx.x;
  int c = tid & 127, lh = tid >> 7;
  const float* xb = x + (size_t)b * NL * NC;
  const float* mb = mask + (size_t)b * NL * NC;
  float sum = 0.f, den = 0.f;
  for (int l = lh; l < NL; l += 2) {
    sum += xb[l * NC + c];
    den += (mb[l * NC + c] == 1.0f) ? 1.f : 0.f;
  }
  __shared__ float ssum[256], sden[256], smean[128], sden2[128];
  ssum[tid] = sum; sden[tid] = den;
  __syncthreads();
  if (lh == 0) {
    float stot = ssum[c] + ssum[c + 128];
    float dtot = sden[c] + sden[c + 128];
    float mn = stot / dtot;
    smean[c] = mn; sden2[c] = dtot;
    means[b * NC + c] = mn;
  }
  __syncthreads();
  float mn = smean[c];
  float sq = 0.f;
  for (int l = lh; l < NL; l += 2) {
    float m = mb[l * NC + c];
    float xv = (m == 0.f) ? 0.f : (xb[l * NC + c] - mn);
    sq += xv * xv;
  }
  __syncthreads();
  ssum[tid] = sq;
  __syncthreads();
  if (lh == 0) {
    stdev[b * NC + c] = sqrtf((ssum[c] + ssum[c + 128]) / sden2[c] + 1e-5f);
  }
}

// ---------------- normalize + transpose (B,L,C) -> (B,C,L) ----------------
__global__ void norm_transpose(const float* __restrict__ x, const float* __restrict__ mask,
                               const float* __restrict__ means, const float* __restrict__ stdev,
                               float* __restrict__ xt) {
  __shared__ float tile[32][33];
  int b = blockIdx.x;
  int l0 = blockIdx.y * 32;
  int c0 = blockIdx.z * 32;
  int tx = threadIdx.x;
  int ty = threadIdx.y;
  for (int i = ty; i < 32; i += 8) {
    int l = l0 + i, c = c0 + tx;
    float v = x[((size_t)b * NL + l) * NC + c];
    float m = mask[((size_t)b * NL + l) * NC + c];
    float val = (m == 0.f) ? 0.f : (v - means[b * NC + c]);
    tile[i][tx] = val / stdev[b * NC + c];
  }
  __syncthreads();
  for (int i = ty; i < 32; i += 8) {
    xt[((size_t)b * NC + c0 + i) * NL + l0 + tx] = tile[tx][i];
  }
}

// ---------------- Haar transform per row (length 1024) ----------------
__global__ void haar_kernel(const float* __restrict__ xt, float* __restrict__ freq) {
  int row = blockIdx.x;
  __shared__ float h[1024], t2[512];
  const float* src = xt + (size_t)row * NL;
  float* dst = freq + (size_t)row * NL;
  for (int i = threadIdx.x; i < 1024; i += 256) h[i] = src[i];
  __syncthreads();
  int n = 1024;
  while (n > 1) {
    int half = n >> 1;
    for (int i = threadIdx.x; i < half; i += 256) {
      float e = h[2 * i], o = h[2 * i + 1];
      dst[half + i] = (e - o) * INV_SQRT2;
      t2[i] = (e + o) * INV_SQRT2;
    }
    __syncthreads();
    for (int i = threadIdx.x; i < half; i += 256) h[i] = t2[i];
    __syncthreads();
    n = half;
  }
  if (threadIdx.x == 0) dst[0] = h[0];
}

// ---------------- f32 -> bf16 convert (n multiple of 4) ----------------
__global__ void cvt_bf16(const float* __restrict__ in, u16* __restrict__ outp, int n4) {
  int i = blockIdx.x * 256 + threadIdx.x;
  if (i < n4) {
    const float4 v = *reinterpret_cast<const float4*>(in + (size_t)i * 4);
    u16x4 o;
    o.x = f2bf(v.x); o.y = f2bf(v.y); o.z = f2bf(v.z); o.w = f2bf(v.w);
    *reinterpret_cast<u16x4*>(outp + (size_t)i * 4) = o;
  }
}

// ---------------- pack conv weights [60][co][ci][k] f32 -> [60][k][co][ci] bf16 ----------------
__global__ void pack_w(const float* __restrict__ w, u16* __restrict__ wp) {
  int idx = blockIdx.x * 256 + threadIdx.x;
  if (idx >= 60 * 5 * 128 * 128) return;
  int ci = idx & 127;
  int co = (idx >> 7) & 127;
  int rest = idx >> 14;
  int k = rest % 5;
  int n = rest / 5;
  wp[idx] = f2bf(w[(((size_t)n * 128 + co) * 128 + ci) * 5 + k]);
}

// ---------------- bf16 MFMA GEMM NT: C[m,n] = epi(sum_k A[m,k]*B[n,k]) ----------------
// EPI 0: relu -> bf16 out; EPI 1: sigmoid -> f32 out
template <int EPI>
__global__ __launch_bounds__(256) void gemm_mfma(const u16* __restrict__ A,
                                                 const u16* __restrict__ Bw,
                                                 u16* __restrict__ Cb, float* __restrict__ Cf,
                                                 int M, int N, int K) {
  __shared__ __align__(16) char sA[128 * 128];  // 128 rows x 64 k x 2B, swizzled
  __shared__ __align__(16) char sB[128 * 128];
  int m0 = blockIdx.y * 128, n0 = blockIdx.x * 128;
  int tid = threadIdx.x;
  int lane = tid & 63, wv = tid >> 6;
  int wm = (wv >> 1) * 64, wn = (wv & 1) * 64;
  int lg = lane >> 4, l15 = lane & 15;
  f32x4 zero = {0.f, 0.f, 0.f, 0.f};
  f32x4 acc[4][4];
#pragma unroll
  for (int i = 0; i < 4; ++i)
#pragma unroll
    for (int j = 0; j < 4; ++j) acc[i][j] = zero;

  for (int k0 = 0; k0 < K; k0 += 64) {
    __syncthreads();
#pragma unroll
    for (int pass = 0; pass < 4; ++pass) {
      int off = pass * 4096 + tid * 16;
      int r = off >> 7, cb = off & 127;
      int sw = r * 128 + (cb ^ ((r & 7) << 4));
      *(u16x8*)(sA + sw) = *(const u16x8*)(A + (size_t)(m0 + r) * K + k0 + (cb >> 1));
      *(u16x8*)(sB + sw) = *(const u16x8*)(Bw + (size_t)(n0 + r) * K + k0 + (cb >> 1));
    }
    __syncthreads();
#pragma unroll
    for (int ks = 0; ks < 2; ++ks) {
      short8 a[4], bb[4];
      int kb = ks * 64 + lg * 16;
#pragma unroll
      for (int mt = 0; mt < 4; ++mt) {
        int r = wm + mt * 16 + l15;
        a[mt] = *(const short8*)(sA + r * 128 + (kb ^ ((r & 7) << 4)));
      }
#pragma unroll
      for (int nt = 0; nt < 4; ++nt) {
        int r = wn + nt * 16 + l15;
        bb[nt] = *(const short8*)(sB + r * 128 + (kb ^ ((r & 7) << 4)));
      }
#pragma unroll
      for (int mt = 0; mt < 4; ++mt)
#pragma unroll
        for (int nt = 0; nt < 4; ++nt)
          acc[mt][nt] = __builtin_amdgcn_mfma_f32_16x16x32_bf16(a[mt], bb[nt], acc[mt][nt], 0, 0, 0);
    }
  }
#pragma unroll
  for (int mt = 0; mt < 4; ++mt)
#pragma unroll
    for (int nt = 0; nt < 4; ++nt)
#pragma unroll
      for (int r = 0; r < 4; ++r) {
        int row = m0 + wm + mt * 16 + lg * 4 + r;
        int col = n0 + wn + nt * 16 + l15;
        float v = acc[mt][nt][r];
        if (EPI == 0) {
          v = v > 0.f ? v : 0.f;
          Cb[(size_t)row * N + col] = f2bf(v);
        } else {
          Cf[(size_t)row * N + col] = 1.f / (1.f + __expf(-v));
        }
      }
}

// ---------------- LayerNorm over last dim (1024) per row, in place ----------------
__global__ void ln_kernel(float* __restrict__ lr, const float* __restrict__ g,
                          const float* __restrict__ bta) {
  int row = blockIdx.x;
  float* p = lr + (size_t)row * 1024;
  int tid = threadIdx.x;
  float v[4];
#pragma unroll
  for (int i = 0; i < 4; ++i) v[i] = p[tid + 256 * i];
  __shared__ float red[256];
  red[tid] = v[0] + v[1] + v[2] + v[3];
  __syncthreads();
  for (int off = 128; off > 0; off >>= 1) {
    if (tid < off) red[tid] += red[tid + off];
    __syncthreads();
  }
  float mu = red[0] * (1.f / 1024.f);
  __syncthreads();
  float sq = 0.f;
#pragma unroll
  for (int i = 0; i < 4; ++i) { float d = v[i] - mu; sq += d * d; }
  red[tid] = sq;
  __syncthreads();
  for (int off = 128; off > 0; off >>= 1) {
    if (tid < off) red[tid] += red[tid + off];
    __syncthreads();
  }
  float rs = rsqrtf(red[0] * (1.f / 1024.f) + 1e-6f);
#pragma unroll
  for (int i = 0; i < 4; ++i) {
    int idx = tid + 256 * i;
    p[idx] = (v[i] - mu) * rs * g[idx] + bta[idx];
  }
}

// ---------------- positional encoding table pe[l][c] ----------------
__global__ void pe_kernel(float* __restrict__ pe) {
  int idx = blockIdx.x * 256 + threadIdx.x;
  int l = idx >> 7, c = idx & 127;
  float inc = logf(10000.f) / 63.f;
  int t = c & 63;
  float inv = expf(-inc * (float)t);
  float st = (float)l * inv;
  pe[idx] = (c < 64) ? sinf(st) : cosf(st);
}

// ---------------- x_t = x_t * lr + pe ----------------
__global__ void combine_kernel(float* __restrict__ xt, const float* __restrict__ lr,
                               const float* __restrict__ pe) {
  size_t idx = (size_t)blockIdx.x * 256 + threadIdx.x;
  int l = (int)(idx & 1023);
  int c = (int)((idx >> 10) & 127);
  xt[idx] = xt[idx] * lr[idx] + pe[(l << 7) | c];
}

// ---------------- fused CIL half-node: MFMA conv1+leaky+conv2+tanh+combine ----------------
// PHASE 0 (branches 0/1): in/oth from parent (interleaved even/odd), out -> xet/xot, mode mul-exp
// PHASE 1 (branches 2/3): in/oth from xot/xet, out -> child buf (or dect if LEAF), mode +/-
constexpr size_t SEGc = (size_t)NB * NC;
constexpr size_t XOT = 2097152;  // elements offset of xot within xet buffer
constexpr int RIN = 88;          // staged input rows (t0-4 .. t0+83)

template <int PHASE, int LEAF>
__global__ __launch_bounds__(256) void ccb_mfma(const float* __restrict__ src,
                                                float* __restrict__ dst,
                                                const u16* __restrict__ wp1,
                                                const u16* __restrict__ wp2,
                                                const float* __restrict__ b1,
                                                const float* __restrict__ b2,
                                                int d, int Tn) {
  __shared__ __align__(16) char lds[RIN * 256];  // [row][128 ci] bf16, 16B-granule XOR swizzle
  int b = blockIdx.x;
  int t0 = blockIdx.y * 64;
  int z = blockIdx.z;
  int p = z >> 1, br = z & 1;
  // preorder node index of (depth d, BFS pos p) in the 15-node tree
  int node = 0;
  for (int i = d - 1; i >= 0; --i) {
    int bit = (p >> i) & 1;
    int dd = d - 1 - i;
    node += 1 + bit * ((1 << (3 - dd)) - 1);
  }
  int widx = node * 4 + PHASE * 2 + br;
  const u16* W1 = wp1 + (size_t)widx * (5 * 128 * 128);
  const u16* W2 = wp2 + (size_t)widx * (5 * 128 * 128);
  const float* B1 = b1 + (size_t)widx * 128;
  const float* B2 = b2 + (size_t)widx * 128;

  const float *inp, *oth;
  float* outp;
  int its, otss, dts;
  size_t irow, orow, drow;
  if (PHASE == 0) {
    const float* par = src + (size_t)p * SEGc * (size_t)(2 * Tn);
    inp = par + (br ? 0 : 1);   // br0: in = xo (odd); br1: in = xe (even)
    oth = par + (br ? 1 : 0);
    its = 2; irow = (size_t)(2 * Tn);
    otss = 2; orow = (size_t)(2 * Tn);
    outp = dst + (br ? XOT : 0) + (size_t)p * SEGc * Tn;
    dts = 1; drow = (size_t)Tn;
  } else {
    inp = src + (br ? 0 : XOT) + (size_t)p * SEGc * Tn;  // br0: in = xot; br1: in = xet
    oth = src + (br ? XOT : 0) + (size_t)p * SEGc * Tn;
    its = 1; irow = (size_t)Tn;
    otss = 1; orow = (size_t)Tn;
    if (!LEAF) {
      outp = dst + (size_t)(2 * p + br) * SEGc * Tn;
      dts = 1; drow = (size_t)Tn;
    } else {
      int rev = ((p & 1) << 2) | (p & 2) | ((p >> 2) & 1);
      outp = dst + rev + br * 8;
      dts = 16; drow = (size_t)NL;
    }
  }

  int tid = threadIdx.x;
  // ---- stage input tile transposed [row=t][ci] bf16, swizzled ----
  const float* inb = inp + (size_t)b * NC * irow;
  for (int c = tid; c < 64 * RIN; c += 256) {
    int pr = c / RIN;          // ci pair index 0..63
    int i = c - pr * RIN;      // row 0..87
    int t = t0 - 4 + i;
    t = t < 0 ? 0 : (t >= Tn ? Tn - 1 : t);
    float v0 = inb[(size_t)(2 * pr) * irow + (size_t)t * its];
    float v1 = inb[(size_t)(2 * pr + 1) * irow + (size_t)t * its];
    unsigned pk = (unsigned)f2bf(v0) | ((unsigned)f2bf(v1) << 16);
    int cbyte = 4 * pr;
    *(unsigned*)(lds + i * 256 + (cbyte ^ ((i & 15) << 4))) = pk;
  }
  __syncthreads();

  int lane = tid & 63, wv = tid >> 6;
  int lg = lane >> 4, l15 = lane & 15;

  // ---- conv1: y[j] = sum_{ci,k} x[j-4+k][ci] w1[k][co][ci], j local 0..79 ----
  f32x4 acc1[2][5];
#pragma unroll
  for (int mt = 0; mt < 2; ++mt) {
    const f32x4 bv = *(const f32x4*)(B1 + wv * 32 + mt * 16 + lg * 4);
#pragma unroll
    for (int nt = 0; nt < 5; ++nt) acc1[mt][nt] = bv;
  }
  for (int k = 0; k < 5; ++k) {
#pragma unroll
    for (int cig = 0; cig < 4; ++cig) {
      int ci0 = cig * 32 + lg * 8;
      short8 a[2], bb[5];
#pragma unroll
      for (int mt = 0; mt < 2; ++mt) {
        int co = wv * 32 + mt * 16 + l15;
        a[mt] = *(const short8*)(W1 + ((size_t)(k * 128 + co) * 128 + ci0));
      }
      int cbyte = 2 * ci0;
#pragma unroll
      for (int nt = 0; nt < 5; ++nt) {
        int i = nt * 16 + l15 + k;
        bb[nt] = *(const short8*)(lds + i * 256 + (cbyte ^ ((i & 15) << 4)));
      }
#pragma unroll
      for (int mt = 0; mt < 2; ++mt)
#pragma unroll
        for (int nt = 0; nt < 5; ++nt)
          acc1[mt][nt] = __builtin_amdgcn_mfma_f32_16x16x32_bf16(a[mt], bb[nt], acc1[mt][nt], 0, 0, 0);
    }
  }
  __syncthreads();  // all conv1 LDS reads complete before overwriting with mid

  // ---- leaky relu, write mid (same LDS buffer, same swizzle) ----
#pragma unroll
  for (int mt = 0; mt < 2; ++mt)
#pragma unroll
    for (int nt = 0; nt < 5; ++nt) {
      int j = nt * 16 + l15;
      int co0 = wv * 32 + mt * 16 + lg * 4;
      u16x4 m;
#pragma unroll
      for (int r = 0; r < 4; ++r) {
        float v = acc1[mt][nt][r];
        v = v > 0.f ? v : 0.01f * v;
        m[r] = f2bf(v);
      }
      *(u16x4*)(lds + j * 256 + ((2 * co0) ^ ((j & 15) << 4))) = m;
    }
  __syncthreads();

  // ---- conv2: z[t] = sum_{ci,k} mid[t+k][ci] w2[k][co][ci], t local 0..63 ----
  f32x4 acc2[2][4];
#pragma unroll
  for (int mt = 0; mt < 2; ++mt) {
    const f32x4 bv = *(const f32x4*)(B2 + wv * 32 + mt * 16 + lg * 4);
#pragma unroll
    for (int nt = 0; nt < 4; ++nt) acc2[mt][nt] = bv;
  }
  for (int k = 0; k < 5; ++k) {
#pragma unroll
    for (int cig = 0; cig < 4; ++cig) {
      int ci0 = cig * 32 + lg * 8;
      short8 a[2], bb[4];
#pragma unroll
      for (int mt = 0; mt < 2; ++mt) {
        int co = wv * 32 + mt * 16 + l15;
        a[mt] = *(const short8*)(W2 + ((size_t)(k * 128 + co) * 128 + ci0));
      }
      int cbyte = 2 * ci0;
#pragma unroll
      for (int nt = 0; nt < 4; ++nt) {
        int i = nt * 16 + l15 + k;
        bb[nt] = *(const short8*)(lds + i * 256 + (cbyte ^ ((i & 15) << 4)));
      }
#pragma unroll
      for (int mt = 0; mt < 2; ++mt)
#pragma unroll
        for (int nt = 0; nt < 4; ++nt)
          acc2[mt][nt] = __builtin_amdgcn_mfma_f32_16x16x32_bf16(a[mt], bb[nt], acc2[mt][nt], 0, 0, 0);
    }
  }

  // ---- tanh + combine + store ----
  const float* othb = oth + (size_t)b * NC * orow;
  float* outb = outp + (size_t)b * NC * drow;
#pragma unroll
  for (int mt = 0; mt < 2; ++mt)
#pragma unroll
    for (int nt = 0; nt < 4; ++nt) {
      int t = t0 + nt * 16 + l15;
#pragma unroll
      for (int r = 0; r < 4; ++r) {
        int co = wv * 32 + mt * 16 + lg * 4 + r;
        float cv = ftanh(acc2[mt][nt][r]);
        float ov = othb[(size_t)co * orow + (size_t)t * otss];
        float res;
        if (PHASE == 0) res = ov * __expf(cv);
        else res = br == 0 ? ov + cv : ov - cv;
        outb[(size_t)co * drow + (size_t)t * dts] = res;
      }
    }
}

// ---------------- final projection + denorm, only p in [0,96), c in [0,3) ----------------
__global__ void final_kernel(const float* __restrict__ dect, const float* __restrict__ xt,
                             const float* __restrict__ projw, const float* __restrict__ means,
                             const float* __restrict__ stdev, float* __restrict__ out) {
  int b = blockIdx.x, p = blockIdx.y;
  int tid = threadIdx.x;
  const float* w = projw + (size_t)(1024 + p) * 1024;
  const float* d0 = dect + (size_t)b * NC * NL;
  const float* x0 = xt + (size_t)b * NC * NL;
  float a[3] = {0.f, 0.f, 0.f};
  for (int l = tid; l < 1024; l += 256) {
    float wv = w[l];
#pragma unroll
    for (int cc = 0; cc < 3; ++cc)
      a[cc] += wv * (d0[(size_t)cc * NL + l] + x0[(size_t)cc * NL + l]);
  }
  __shared__ float red[3][256];
  for (int cc = 0; cc < 3; ++cc) red[cc][tid] = a[cc];
  __syncthreads();
  for (int off = 128; off > 0; off >>= 1) {
    if (tid < off) {
      red[0][tid] += red[0][tid + off];
      red[1][tid] += red[1][tid + off];
      red[2][tid] += red[2][tid + off];
    }
    __syncthreads();
  }
  if (tid < 3) {
    out[((size_t)b * NP + p) * 3 + tid] = red[tid][0] * stdev[b * NC + tid] + means[b * NC + tid];
  }
}

}  // namespace

extern "C" void kernel_launch(void* const* d_in, const int* in_sizes, int n_in,
                              void* d_out, int out_size, void* d_ws, size_t ws_size,
                              hipStream_t stream) {
  (void)in_sizes; (void)n_in; (void)out_size; (void)ws_size;
  const float* x_enc = (const float*)d_in[0];
  const float* mask  = (const float*)d_in[1];
  const float* fc1_w = (const float*)d_in[2];
  const float* fc2_w = (const float*)d_in[3];
  const float* ln_g  = (const float*)d_in[4];
  const float* ln_b  = (const float*)d_in[5];
  const float* w1    = (const float*)d_in[6];
  const float* b1    = (const float*)d_in[7];
  const float* w2    = (const float*)d_in[8];
  const float* b2    = (const float*)d_in[9];
  const float* projw = (const float*)d_in[10];
  float* out = (float*)d_out;
  float* ws = (float*)d_ws;

  // workspace layout (floats), total 26,025,984 floats ~= 104.1 MB
  float* means = ws + 0;          // 4096
  float* stdev = ws + 4096;       // 4096
  float* pe    = ws + 8192;       // 131072
  float* x_t   = ws + 139264;     // 4,194,304  (B,C,L) fp32, depth-0 buf, kept to end
  float* freq  = ws + 4333568;    // 4,194,304  haar fp32 -> lr fp32 -> IN3 (depth-3 buf)
  float* IN1   = ws + 8527872;    // 4,194,304  hid_bf (bf16) -> depth-1 buf
  float* IN2   = ws + 12722176;   // 4,194,304  fc1/fc2 bf16 -> depth-2 buf -> dect
  float* xet   = ws + 16916480;   // 2,097,152  freq_bf (bf16) alias -> xet
  float* xot   = ws + 19013632;   // 2,097,152  (xet+XOT)
  float* wp1f  = ws + 21110784;   // 2,457,600  packed conv w1 bf16
  float* wp2f  = ws + 23568384;   // 2,457,600  packed conv w2 bf16
  (void)xot;
  float* dect = IN2;
  u16* freq_bf = (u16*)xet;
  u16* hid_bf  = (u16*)IN1;
  u16* fc1w_bf = (u16*)IN2;
  u16* fc2w_bf = (u16*)(IN2 + 1048576);
  u16* wp1 = (u16*)wp1f;
  u16* wp2 = (u16*)wp2f;

  stats_kernel<<<NB, 256, 0, stream>>>(x_enc, mask, means, stdev);
  norm_transpose<<<dim3(NB, NL / 32, NC / 32), dim3(32, 8), 0, stream>>>(x_enc, mask, means, stdev, x_t);
  haar_kernel<<<NB * NC, 256, 0, stream>>>(x_t, freq);

  cvt_bf16<<<4096, 256, 0, stream>>>(freq, freq_bf, 1048576);
  cvt_bf16<<<2048, 256, 0, stream>>>(fc1_w, fc1w_bf, 524288);
  cvt_bf16<<<2048, 256, 0, stream>>>(fc2_w, fc2w_bf, 524288);
  pack_w<<<19200, 256, 0, stream>>>(w1, wp1);
  pack_w<<<19200, 256, 0, stream>>>(w2, wp2);

  gemm_mfma<0><<<dim3(16, 32), 256, 0, stream>>>(freq_bf, fc1w_bf, hid_bf, nullptr, 4096, 2048, 1024);
  gemm_mfma<1><<<dim3(8, 32), 256, 0, stream>>>(hid_bf, fc2w_bf, nullptr, freq, 4096, 1024, 2048);

  ln_kernel<<<4096, 256, 0, stream>>>(freq, ln_g, ln_b);
  pe_kernel<<<(NL * NC) / 256, 256, 0, stream>>>(pe);
  combine_kernel<<<(NB * NC * NL) / 256, 256, 0, stream>>>(x_t, freq, pe);

  float* depthbuf[4] = {x_t, IN1, IN2, freq};
  for (int d = 0; d < 4; ++d) {
    int Tn = 512 >> d;
    int nsub = 1 << d;
    dim3 grid(NB, Tn / 64, 2 * nsub);
    ccb_mfma<0, 0><<<grid, 256, 0, stream>>>(depthbuf[d], xet, wp1, wp2, b1, b2, d, Tn);
    if (d < 3) {
      ccb_mfma<1, 0><<<grid, 256, 0, stream>>>(xet, depthbuf[d + 1], wp1, wp2, b1, b2, d, Tn);
    } else {
      ccb_mfma<1, 1><<<grid, 256, 0, stream>>>(xet, dect, wp1, wp2, b1, b2, d, Tn);
    }
  }

  final_kernel<<<dim3(NB, NP), 256, 0, stream>>>(dect, x_t, projw, means, stdev, out);
}

// Round 3
// 425.038 us; speedup vs baseline: 13.8171x; 1.5505x over previous
//
#include <hip/hip_runtime.h>

namespace {

constexpr int NB = 32, NL = 1024, NC = 128, NP = 96, KW = 5;
constexpr float INV_SQRT2 = 0.70710678118654752440f;

typedef unsigned short u16;
typedef __attribute__((ext_vector_type(4))) u16 u16x4;
typedef __attribute__((ext_vector_type(8))) u16 u16x8;
typedef __attribute__((ext_vector_type(8))) short short8;
typedef __attribute__((ext_vector_type(4))) float f32x4;

__device__ inline u16 f2bf(float f) {
  unsigned u = __float_as_uint(f);
  u += 0x7fff + ((u >> 16) & 1);
  return (u16)(u >> 16);
}

__device__ inline float ftanh(float x) {
  float e = __expf(2.f * x);
  return 1.f - 2.f / (e + 1.f);
}

// ---------------- stats stage 1: per (b, L-slice) partial sums ----------------
// part[((b*16+s)*5+q)*NC+c]: q=0 S_all, 1 D(mask==1), 2 Sm(mask!=0), 3 Sm2, 4 Cnz(mask!=0)
__global__ void stats1(const float* __restrict__ x, const float* __restrict__ mask,
                       float* __restrict__ part) {
  int b = blockIdx.x, s = blockIdx.y;
  int tid = threadIdx.x;
  int c = tid & 127, lh = tid >> 7;
  const float* xb = x + (size_t)b * NL * NC;
  const float* mb = mask + (size_t)b * NL * NC;
  float s_all = 0.f, d1 = 0.f, sm = 0.f, sm2 = 0.f, cnz = 0.f;
#pragma unroll 4
  for (int i = 0; i < 32; ++i) {
    int l = s * 64 + lh + 2 * i;
    float v = xb[(size_t)l * NC + c];
    float m = mb[(size_t)l * NC + c];
    s_all += v;
    d1 += (m == 1.f) ? 1.f : 0.f;
    bool nz = (m != 0.f);
    float vm = nz ? v : 0.f;
    sm += vm;
    sm2 += vm * v;
    cnz += nz ? 1.f : 0.f;
  }
  __shared__ float red[5][256];
  red[0][tid] = s_all; red[1][tid] = d1; red[2][tid] = sm;
  red[3][tid] = sm2;   red[4][tid] = cnz;
  __syncthreads();
  if (lh == 0) {
    float* pp = part + ((size_t)(b * 16 + s) * 5) * NC + c;
#pragma unroll
    for (int q = 0; q < 5; ++q) pp[q * NC] = red[q][c] + red[q][c + 128];
  }
}

// ---------------- stats stage 2: combine slices -> means, stdev ----------------
__global__ void stats2(const float* __restrict__ part, float* __restrict__ means,
                       float* __restrict__ stdev) {
  int b = blockIdx.x, c = threadIdx.x;  // 128 threads
  float s_all = 0.f, d1 = 0.f, sm = 0.f, sm2 = 0.f, cnz = 0.f;
  for (int s = 0; s < 16; ++s) {
    const float* pp = part + ((size_t)(b * 16 + s) * 5) * NC + c;
    s_all += pp[0];
    d1    += pp[NC];
    sm    += pp[2 * NC];
    sm2   += pp[3 * NC];
    cnz   += pp[4 * NC];
  }
  float mn = s_all / d1;
  float varsum = sm2 - 2.f * mn * sm + mn * mn * cnz;
  means[b * NC + c] = mn;
  stdev[b * NC + c] = sqrtf(varsum / d1 + 1e-5f);
}

// ---------------- normalize + transpose (B,L,C) -> (B,C,L) ----------------
__global__ void norm_transpose(const float* __restrict__ x, const float* __restrict__ mask,
                               const float* __restrict__ means, const float* __restrict__ stdev,
                               float* __restrict__ xt) {
  __shared__ float tile[32][33];
  int b = blockIdx.x;
  int l0 = blockIdx.y * 32;
  int c0 = blockIdx.z * 32;
  int tx = threadIdx.x;
  int ty = threadIdx.y;
  for (int i = ty; i < 32; i += 8) {
    int l = l0 + i, c = c0 + tx;
    float v = x[((size_t)b * NL + l) * NC + c];
    float m = mask[((size_t)b * NL + l) * NC + c];
    float val = (m == 0.f) ? 0.f : (v - means[b * NC + c]);
    tile[i][tx] = val / stdev[b * NC + c];
  }
  __syncthreads();
  for (int i = ty; i < 32; i += 8) {
    xt[((size_t)b * NC + c0 + i) * NL + l0 + tx] = tile[tx][i];
  }
}

// ---------------- Haar transform per row (length 1024) ----------------
__global__ void haar_kernel(const float* __restrict__ xt, float* __restrict__ freq) {
  int row = blockIdx.x;
  __shared__ float h[1024], t2[512];
  const float* src = xt + (size_t)row * NL;
  float* dst = freq + (size_t)row * NL;
  for (int i = threadIdx.x; i < 1024; i += 256) h[i] = src[i];
  __syncthreads();
  int n = 1024;
  while (n > 1) {
    int half = n >> 1;
    for (int i = threadIdx.x; i < half; i += 256) {
      float e = h[2 * i], o = h[2 * i + 1];
      dst[half + i] = (e - o) * INV_SQRT2;
      t2[i] = (e + o) * INV_SQRT2;
    }
    __syncthreads();
    for (int i = threadIdx.x; i < half; i += 256) h[i] = t2[i];
    __syncthreads();
    n = half;
  }
  if (threadIdx.x == 0) dst[0] = h[0];
}

// ---------------- f32 -> bf16 convert (n multiple of 4) ----------------
__global__ void cvt_bf16(const float* __restrict__ in, u16* __restrict__ outp, int n4) {
  int i = blockIdx.x * 256 + threadIdx.x;
  if (i < n4) {
    const float4 v = *reinterpret_cast<const float4*>(in + (size_t)i * 4);
    u16x4 o;
    o.x = f2bf(v.x); o.y = f2bf(v.y); o.z = f2bf(v.z); o.w = f2bf(v.w);
    *reinterpret_cast<u16x4*>(outp + (size_t)i * 4) = o;
  }
}

// ---------------- pack conv weights [60][co][ci][k] f32 -> [60][k][co][ci] bf16 ----------------
__global__ void pack_w(const float* __restrict__ w, u16* __restrict__ wp) {
  int idx = blockIdx.x * 256 + threadIdx.x;
  if (idx >= 60 * 5 * 128 * 128) return;
  int ci = idx & 127;
  int co = (idx >> 7) & 127;
  int rest = idx >> 14;
  int k = rest % 5;
  int n = rest / 5;
  wp[idx] = f2bf(w[(((size_t)n * 128 + co) * 128 + ci) * 5 + k]);
}

// ---------------- bf16 MFMA GEMM NT: C[m,n] = epi(sum_k A[m,k]*B[n,k]) ----------------
// EPI 0: relu -> bf16 out; EPI 1: sigmoid -> f32 out
template <int EPI>
__global__ __launch_bounds__(256) void gemm_mfma(const u16* __restrict__ A,
                                                 const u16* __restrict__ Bw,
                                                 u16* __restrict__ Cb, float* __restrict__ Cf,
                                                 int M, int N, int K) {
  __shared__ __align__(16) char sA[128 * 128];  // 128 rows x 64 k x 2B, swizzled
  __shared__ __align__(16) char sB[128 * 128];
  int m0 = blockIdx.y * 128, n0 = blockIdx.x * 128;
  int tid = threadIdx.x;
  int lane = tid & 63, wv = tid >> 6;
  int wm = (wv >> 1) * 64, wn = (wv & 1) * 64;
  int lg = lane >> 4, l15 = lane & 15;
  f32x4 zero = {0.f, 0.f, 0.f, 0.f};
  f32x4 acc[4][4];
#pragma unroll
  for (int i = 0; i < 4; ++i)
#pragma unroll
    for (int j = 0; j < 4; ++j) acc[i][j] = zero;

  for (int k0 = 0; k0 < K; k0 += 64) {
    __syncthreads();
#pragma unroll
    for (int pass = 0; pass < 4; ++pass) {
      int off = pass * 4096 + tid * 16;
      int r = off >> 7, cb = off & 127;
      int sw = r * 128 + (cb ^ ((r & 7) << 4));
      *(u16x8*)(sA + sw) = *(const u16x8*)(A + (size_t)(m0 + r) * K + k0 + (cb >> 1));
      *(u16x8*)(sB + sw) = *(const u16x8*)(Bw + (size_t)(n0 + r) * K + k0 + (cb >> 1));
    }
    __syncthreads();
#pragma unroll
    for (int ks = 0; ks < 2; ++ks) {
      short8 a[4], bb[4];
      int kb = ks * 64 + lg * 16;
#pragma unroll
      for (int mt = 0; mt < 4; ++mt) {
        int r = wm + mt * 16 + l15;
        a[mt] = *(const short8*)(sA + r * 128 + (kb ^ ((r & 7) << 4)));
      }
#pragma unroll
      for (int nt = 0; nt < 4; ++nt) {
        int r = wn + nt * 16 + l15;
        bb[nt] = *(const short8*)(sB + r * 128 + (kb ^ ((r & 7) << 4)));
      }
#pragma unroll
      for (int mt = 0; mt < 4; ++mt)
#pragma unroll
        for (int nt = 0; nt < 4; ++nt)
          acc[mt][nt] = __builtin_amdgcn_mfma_f32_16x16x32_bf16(a[mt], bb[nt], acc[mt][nt], 0, 0, 0);
    }
  }
#pragma unroll
  for (int mt = 0; mt < 4; ++mt)
#pragma unroll
    for (int nt = 0; nt < 4; ++nt)
#pragma unroll
      for (int r = 0; r < 4; ++r) {
        int row = m0 + wm + mt * 16 + lg * 4 + r;
        int col = n0 + wn + nt * 16 + l15;
        float v = acc[mt][nt][r];
        if (EPI == 0) {
          v = v > 0.f ? v : 0.f;
          Cb[(size_t)row * N + col] = f2bf(v);
        } else {
          Cf[(size_t)row * N + col] = 1.f / (1.f + __expf(-v));
        }
      }
}

// ---------------- LayerNorm over last dim (1024) per row, in place ----------------
__global__ void ln_kernel(float* __restrict__ lr, const float* __restrict__ g,
                          const float* __restrict__ bta) {
  int row = blockIdx.x;
  float* p = lr + (size_t)row * 1024;
  int tid = threadIdx.x;
  float v[4];
#pragma unroll
  for (int i = 0; i < 4; ++i) v[i] = p[tid + 256 * i];
  __shared__ float red[256];
  red[tid] = v[0] + v[1] + v[2] + v[3];
  __syncthreads();
  for (int off = 128; off > 0; off >>= 1) {
    if (tid < off) red[tid] += red[tid + off];
    __syncthreads();
  }
  float mu = red[0] * (1.f / 1024.f);
  __syncthreads();
  float sq = 0.f;
#pragma unroll
  for (int i = 0; i < 4; ++i) { float d = v[i] - mu; sq += d * d; }
  red[tid] = sq;
  __syncthreads();
  for (int off = 128; off > 0; off >>= 1) {
    if (tid < off) red[tid] += red[tid + off];
    __syncthreads();
  }
  float rs = rsqrtf(red[0] * (1.f / 1024.f) + 1e-6f);
#pragma unroll
  for (int i = 0; i < 4; ++i) {
    int idx = tid + 256 * i;
    p[idx] = (v[i] - mu) * rs * g[idx] + bta[idx];
  }
}

// ---------------- positional encoding table pe[l][c] ----------------
__global__ void pe_kernel(float* __restrict__ pe) {
  int idx = blockIdx.x * 256 + threadIdx.x;
  int l = idx >> 7, c = idx & 127;
  float inc = logf(10000.f) / 63.f;
  int t = c & 63;
  float inv = expf(-inc * (float)t);
  float st = (float)l * inv;
  pe[idx] = (c < 64) ? sinf(st) : cosf(st);
}

// ---------------- x_t = x_t * lr + pe ----------------
__global__ void combine_kernel(float* __restrict__ xt, const float* __restrict__ lr,
                               const float* __restrict__ pe) {
  size_t idx = (size_t)blockIdx.x * 256 + threadIdx.x;
  int l = (int)(idx & 1023);
  int c = (int)((idx >> 10) & 127);
  xt[idx] = xt[idx] * lr[idx] + pe[(l << 7) | c];
}

// ---------------- fused CIL half-node: MFMA conv1+leaky+conv2+tanh+combine ----------------
// PHASE 0 (branches 0/1): in/oth from parent (interleaved even/odd), out -> xet/xot, mode mul-exp
// PHASE 1 (branches 2/3): in/oth from xot/xet, out -> child buf (or dect if LEAF), mode +/-
constexpr size_t SEGc = (size_t)NB * NC;
constexpr size_t XOT = 2097152;  // elements offset of xot within xet buffer
constexpr int RIN = 88;          // staged input rows (t0-4 .. t0+83)

template <int PHASE, int LEAF>
__global__ __launch_bounds__(256) void ccb_mfma(const float* __restrict__ src,
                                                float* __restrict__ dst,
                                                const u16* __restrict__ wp1,
                                                const u16* __restrict__ wp2,
                                                const float* __restrict__ b1,
                                                const float* __restrict__ b2,
                                                int d, int Tn) {
  __shared__ __align__(16) char lds[RIN * 256];  // [row][128 ci] bf16, 16B-granule XOR swizzle
  int b = blockIdx.x;
  int t0 = blockIdx.y * 64;
  int z = blockIdx.z;
  int p = z >> 1, br = z & 1;
  // preorder node index of (depth d, BFS pos p) in the 15-node tree
  int node = 0;
  for (int i = d - 1; i >= 0; --i) {
    int bit = (p >> i) & 1;
    int dd = d - 1 - i;
    node += 1 + bit * ((1 << (3 - dd)) - 1);
  }
  int widx = node * 4 + PHASE * 2 + br;
  const u16* W1 = wp1 + (size_t)widx * (5 * 128 * 128);
  const u16* W2 = wp2 + (size_t)widx * (5 * 128 * 128);
  const float* B1 = b1 + (size_t)widx * 128;
  const float* B2 = b2 + (size_t)widx * 128;

  const float *inp, *oth;
  float* outp;
  int its, otss, dts;
  size_t irow, orow, drow;
  if (PHASE == 0) {
    const float* par = src + (size_t)p * SEGc * (size_t)(2 * Tn);
    inp = par + (br ? 0 : 1);   // br0: in = xo (odd); br1: in = xe (even)
    oth = par + (br ? 1 : 0);
    its = 2; irow = (size_t)(2 * Tn);
    otss = 2; orow = (size_t)(2 * Tn);
    outp = dst + (br ? XOT : 0) + (size_t)p * SEGc * Tn;
    dts = 1; drow = (size_t)Tn;
  } else {
    inp = src + (br ? 0 : XOT) + (size_t)p * SEGc * Tn;  // br0: in = xot; br1: in = xet
    oth = src + (br ? XOT : 0) + (size_t)p * SEGc * Tn;
    its = 1; irow = (size_t)Tn;
    otss = 1; orow = (size_t)Tn;
    if (!LEAF) {
      outp = dst + (size_t)(2 * p + br) * SEGc * Tn;
      dts = 1; drow = (size_t)Tn;
    } else {
      int rev = ((p & 1) << 2) | (p & 2) | ((p >> 2) & 1);
      outp = dst + rev + br * 8;
      dts = 16; drow = (size_t)NL;
    }
  }

  int tid = threadIdx.x;
  // ---- stage input tile transposed [row=t][ci] bf16, swizzled ----
  const float* inb = inp + (size_t)b * NC * irow;
  for (int c = tid; c < 64 * RIN; c += 256) {
    int pr = c / RIN;          // ci pair index 0..63
    int i = c - pr * RIN;      // row 0..87
    int t = t0 - 4 + i;
    t = t < 0 ? 0 : (t >= Tn ? Tn - 1 : t);
    float v0 = inb[(size_t)(2 * pr) * irow + (size_t)t * its];
    float v1 = inb[(size_t)(2 * pr + 1) * irow + (size_t)t * its];
    unsigned pk = (unsigned)f2bf(v0) | ((unsigned)f2bf(v1) << 16);
    int cbyte = 4 * pr;
    *(unsigned*)(lds + i * 256 + (cbyte ^ ((i & 15) << 4))) = pk;
  }
  __syncthreads();

  int lane = tid & 63, wv = tid >> 6;
  int lg = lane >> 4, l15 = lane & 15;

  // ---- conv1: y[j] = sum_{ci,k} x[j-4+k][ci] w1[k][co][ci], j local 0..79 ----
  f32x4 acc1[2][5];
#pragma unroll
  for (int mt = 0; mt < 2; ++mt) {
    const f32x4 bv = *(const f32x4*)(B1 + wv * 32 + mt * 16 + lg * 4);
#pragma unroll
    for (int nt = 0; nt < 5; ++nt) acc1[mt][nt] = bv;
  }
  for (int k = 0; k < 5; ++k) {
#pragma unroll
    for (int cig = 0; cig < 4; ++cig) {
      int ci0 = cig * 32 + lg * 8;
      short8 a[2], bb[5];
#pragma unroll
      for (int mt = 0; mt < 2; ++mt) {
        int co = wv * 32 + mt * 16 + l15;
        a[mt] = *(const short8*)(W1 + ((size_t)(k * 128 + co) * 128 + ci0));
      }
      int cbyte = 2 * ci0;
#pragma unroll
      for (int nt = 0; nt < 5; ++nt) {
        int i = nt * 16 + l15 + k;
        bb[nt] = *(const short8*)(lds + i * 256 + (cbyte ^ ((i & 15) << 4)));
      }
#pragma unroll
      for (int mt = 0; mt < 2; ++mt)
#pragma unroll
        for (int nt = 0; nt < 5; ++nt)
          acc1[mt][nt] = __builtin_amdgcn_mfma_f32_16x16x32_bf16(a[mt], bb[nt], acc1[mt][nt], 0, 0, 0);
    }
  }
  __syncthreads();  // all conv1 LDS reads complete before overwriting with mid

  // ---- leaky relu, write mid (same LDS buffer, same swizzle) ----
#pragma unroll
  for (int mt = 0; mt < 2; ++mt)
#pragma unroll
    for (int nt = 0; nt < 5; ++nt) {
      int j = nt * 16 + l15;
      int co0 = wv * 32 + mt * 16 + lg * 4;
      u16x4 m;
#pragma unroll
      for (int r = 0; r < 4; ++r) {
        float v = acc1[mt][nt][r];
        v = v > 0.f ? v : 0.01f * v;
        m[r] = f2bf(v);
      }
      *(u16x4*)(lds + j * 256 + ((2 * co0) ^ ((j & 15) << 4))) = m;
    }
  __syncthreads();

  // ---- conv2: z[t] = sum_{ci,k} mid[t+k][ci] w2[k][co][ci], t local 0..63 ----
  f32x4 acc2[2][4];
#pragma unroll
  for (int mt = 0; mt < 2; ++mt) {
    const f32x4 bv = *(const f32x4*)(B2 + wv * 32 + mt * 16 + lg * 4);
#pragma unroll
    for (int nt = 0; nt < 4; ++nt) acc2[mt][nt] = bv;
  }
  for (int k = 0; k < 5; ++k) {
#pragma unroll
    for (int cig = 0; cig < 4; ++cig) {
      int ci0 = cig * 32 + lg * 8;
      short8 a[2], bb[4];
#pragma unroll
      for (int mt = 0; mt < 2; ++mt) {
        int co = wv * 32 + mt * 16 + l15;
        a[mt] = *(const short8*)(W2 + ((size_t)(k * 128 + co) * 128 + ci0));
      }
      int cbyte = 2 * ci0;
#pragma unroll
      for (int nt = 0; nt < 4; ++nt) {
        int i = nt * 16 + l15 + k;
        bb[nt] = *(const short8*)(lds + i * 256 + (cbyte ^ ((i & 15) << 4)));
      }
#pragma unroll
      for (int mt = 0; mt < 2; ++mt)
#pragma unroll
        for (int nt = 0; nt < 4; ++nt)
          acc2[mt][nt] = __builtin_amdgcn_mfma_f32_16x16x32_bf16(a[mt], bb[nt], acc2[mt][nt], 0, 0, 0);
    }
  }

  // ---- tanh + combine + store ----
  const float* othb = oth + (size_t)b * NC * orow;
  float* outb = outp + (size_t)b * NC * drow;
#pragma unroll
  for (int mt = 0; mt < 2; ++mt)
#pragma unroll
    for (int nt = 0; nt < 4; ++nt) {
      int t = t0 + nt * 16 + l15;
#pragma unroll
      for (int r = 0; r < 4; ++r) {
        int co = wv * 32 + mt * 16 + lg * 4 + r;
        float cv = ftanh(acc2[mt][nt][r]);
        float ov = othb[(size_t)co * orow + (size_t)t * otss];
        float res;
        if (PHASE == 0) res = ov * __expf(cv);
        else res = br == 0 ? ov + cv : ov - cv;
        outb[(size_t)co * drow + (size_t)t * dts] = res;
      }
    }
}

// ---------------- final projection + denorm, only p in [0,96), c in [0,3) ----------------
__global__ void final_kernel(const float* __restrict__ dect, const float* __restrict__ xt,
                             const float* __restrict__ projw, const float* __restrict__ means,
                             const float* __restrict__ stdev, float* __restrict__ out) {
  int b = blockIdx.x, p = blockIdx.y;
  int tid = threadIdx.x;
  const float* w = projw + (size_t)(1024 + p) * 1024;
  const float* d0 = dect + (size_t)b * NC * NL;
  const float* x0 = xt + (size_t)b * NC * NL;
  float a[3] = {0.f, 0.f, 0.f};
  for (int l = tid; l < 1024; l += 256) {
    float wv = w[l];
#pragma unroll
    for (int cc = 0; cc < 3; ++cc)
      a[cc] += wv * (d0[(size_t)cc * NL + l] + x0[(size_t)cc * NL + l]);
  }
  __shared__ float red[3][256];
  for (int cc = 0; cc < 3; ++cc) red[cc][tid] = a[cc];
  __syncthreads();
  for (int off = 128; off > 0; off >>= 1) {
    if (tid < off) {
      red[0][tid] += red[0][tid + off];
      red[1][tid] += red[1][tid + off];
      red[2][tid] += red[2][tid + off];
    }
    __syncthreads();
  }
  if (tid < 3) {
    out[((size_t)b * NP + p) * 3 + tid] = red[tid][0] * stdev[b * NC + tid] + means[b * NC + tid];
  }
}

}  // namespace

extern "C" void kernel_launch(void* const* d_in, const int* in_sizes, int n_in,
                              void* d_out, int out_size, void* d_ws, size_t ws_size,
                              hipStream_t stream) {
  (void)in_sizes; (void)n_in; (void)out_size; (void)ws_size;
  const float* x_enc = (const float*)d_in[0];
  const float* mask  = (const float*)d_in[1];
  const float* fc1_w = (const float*)d_in[2];
  const float* fc2_w = (const float*)d_in[3];
  const float* ln_g  = (const float*)d_in[4];
  const float* ln_b  = (const float*)d_in[5];
  const float* w1    = (const float*)d_in[6];
  const float* b1    = (const float*)d_in[7];
  const float* w2    = (const float*)d_in[8];
  const float* b2    = (const float*)d_in[9];
  const float* projw = (const float*)d_in[10];
  float* out = (float*)d_out;
  float* ws = (float*)d_ws;

  // workspace layout (floats), total 26,025,984 floats ~= 104.1 MB
  float* means = ws + 0;          // 4096
  float* stdev = ws + 4096;       // 4096
  float* pe    = ws + 8192;       // 131072
  float* x_t   = ws + 139264;     // 4,194,304  (B,C,L) fp32, depth-0 buf, kept to end
  float* freq  = ws + 4333568;    // 4,194,304  haar fp32 -> lr fp32 -> IN3 (depth-3 buf)
  float* IN1   = ws + 8527872;    // 4,194,304  hid_bf (bf16) -> depth-1 buf
  float* IN2   = ws + 12722176;   // 4,194,304  fc1/fc2 bf16 -> depth-2 buf -> dect
  float* xet   = ws + 16916480;   // 2,097,152  freq_bf (bf16) alias -> xet
  float* xot   = ws + 19013632;   // 2,097,152  (xet+XOT)
  float* wp1f  = ws + 21110784;   // 2,457,600  stats partials (early) -> packed conv w1 bf16
  float* wp2f  = ws + 23568384;   // 2,457,600  packed conv w2 bf16
  (void)xot;
  float* dect = IN2;
  float* stats_part = wp1f;       // 327,680 floats, consumed before pack_w overwrites
  u16* freq_bf = (u16*)xet;
  u16* hid_bf  = (u16*)IN1;
  u16* fc1w_bf = (u16*)IN2;
  u16* fc2w_bf = (u16*)(IN2 + 1048576);
  u16* wp1 = (u16*)wp1f;
  u16* wp2 = (u16*)wp2f;

  stats1<<<dim3(NB, 16), 256, 0, stream>>>(x_enc, mask, stats_part);
  stats2<<<NB, 128, 0, stream>>>(stats_part, means, stdev);
  norm_transpose<<<dim3(NB, NL / 32, NC / 32), dim3(32, 8), 0, stream>>>(x_enc, mask, means, stdev, x_t);
  haar_kernel<<<NB * NC, 256, 0, stream>>>(x_t, freq);

  cvt_bf16<<<4096, 256, 0, stream>>>(freq, freq_bf, 1048576);
  cvt_bf16<<<2048, 256, 0, stream>>>(fc1_w, fc1w_bf, 524288);
  cvt_bf16<<<2048, 256, 0, stream>>>(fc2_w, fc2w_bf, 524288);
  pack_w<<<19200, 256, 0, stream>>>(w1, wp1);
  pack_w<<<19200, 256, 0, stream>>>(w2, wp2);

  gemm_mfma<0><<<dim3(16, 32), 256, 0, stream>>>(freq_bf, fc1w_bf, hid_bf, nullptr, 4096, 2048, 1024);
  gemm_mfma<1><<<dim3(8, 32), 256, 0, stream>>>(hid_bf, fc2w_bf, nullptr, freq, 4096, 1024, 2048);

  ln_kernel<<<4096, 256, 0, stream>>>(freq, ln_g, ln_b);
  pe_kernel<<<(NL * NC) / 256, 256, 0, stream>>>(pe);
  combine_kernel<<<(NB * NC * NL) / 256, 256, 0, stream>>>(x_t, freq, pe);

  float* depthbuf[4] = {x_t, IN1, IN2, freq};
  for (int d = 0; d < 4; ++d) {
    int Tn = 512 >> d;
    int nsub = 1 << d;
    dim3 grid(NB, Tn / 64, 2 * nsub);
    ccb_mfma<0, 0><<<grid, 256, 0, stream>>>(depthbuf[d], xet, wp1, wp2, b1, b2, d, Tn);
    if (d < 3) {
      ccb_mfma<1, 0><<<grid, 256, 0, stream>>>(xet, depthbuf[d + 1], wp1, wp2, b1, b2, d, Tn);
    } else {
      ccb_mfma<1, 1><<<grid, 256, 0, stream>>>(xet, dect, wp1, wp2, b1, b2, d, Tn);
    }
  }

  final_kernel<<<dim3(NB, NP), 256, 0, stream>>>(dect, x_t, projw, means, stdev, out);
}